// Round 5
// baseline (99.222 us; speedup 1.0000x reference)
//
#include <hip/hip_runtime.h>
#include <hip/hip_bf16.h>

#define BLOCK   256
#define QPT     8      // queries per thread
#define DCHUNKS 64     // db split into this many chunks (grid.y)
#define CHUNK   256    // db points per chunk = 16384/64

typedef __attribute__((ext_vector_type(2))) float f32x2;

// Pack both clouds two ways:
//  P  : float4 (x,y,z,|p|^2) per point            -> query-role loads
//  T  : pair-transposed {x0,x1,y0,y1,z0,z1,w0,w1} -> db-role packed operands
// Also init min arrays to +inf bits and zero the output accumulator.
__global__ __launch_bounds__(BLOCK) void chamfer_prep(
    const float* __restrict__ Xc, const float* __restrict__ Xt,
    float4* __restrict__ Pc, float4* __restrict__ Pt,
    float* __restrict__ Tc, float* __restrict__ Tt,
    unsigned* __restrict__ minC, unsigned* __restrict__ minT,
    float* __restrict__ out, int n, int m)
{
    int i = blockIdx.x * BLOCK + threadIdx.x;
    if (i == 0) out[0] = 0.0f;
    if (i < n) {
        float x = Xc[i * 3 + 0], y = Xc[i * 3 + 1], z = Xc[i * 3 + 2];
        float w = x * x + y * y + z * z;
        Pc[i] = make_float4(x, y, z, w);
        minC[i] = 0xFFFFFFFFu;
        float* T = Tc + 8 * (i >> 1);
        int l = i & 1;
        T[0 + l] = x; T[2 + l] = y; T[4 + l] = z; T[6 + l] = w;
    }
    if (i < m) {
        float x = Xt[i * 3 + 0], y = Xt[i * 3 + 1], z = Xt[i * 3 + 2];
        float w = x * x + y * y + z * z;
        Pt[i] = make_float4(x, y, z, w);
        minT[i] = 0xFFFFFFFFu;
        float* T = Tt + 8 * (i >> 1);
        int l = i & 1;
        T[0 + l] = x; T[2 + l] = y; T[4 + l] = z; T[6 + l] = w;
    }
}

// Both directions in one launch (blockIdx.z picks roles). db chunk staged in
// LDS in pair-transposed form; inner loop is v_pk_fma_f32 (2 fp32 FMA/inst)
// + v_min3_f32 chains. Tracks min over db of (|p|^2 - 2 q.p); q^2 in epilogue.
__global__ __launch_bounds__(BLOCK) void chamfer_pass(
    const float4* __restrict__ Pc, const float4* __restrict__ Pt,
    const float4* __restrict__ Tc4, const float4* __restrict__ Tt4,
    unsigned* __restrict__ minC, unsigned* __restrict__ minT)
{
    __shared__ float4 tile[CHUNK];   // CHUNK/2 pairs x 32B

    const float4* q; const float4* dbT; unsigned* minOut;
    if (blockIdx.z == 0) { q = Pc; dbT = Tt4; minOut = minC; }
    else                 { q = Pt; dbT = Tc4; minOut = minT; }

    const int qbase = blockIdx.x * (BLOCK * QPT);
    const int dbase = blockIdx.y * CHUNK;   // point idx == float4 idx into T

    // Stage db chunk (coalesced float4 copy)
    tile[threadIdx.x] = dbT[dbase + threadIdx.x];

    // This thread's QPT query points: premultiply by -2, splat into f32x2
    f32x2 qx2[QPT], qy2[QPT], qz2[QPT], mn[QPT];
    float q2[QPT];
#pragma unroll
    for (int k = 0; k < QPT; ++k) {
        float4 v = q[qbase + k * BLOCK + threadIdx.x];
        float ax = -2.0f * v.x, ay = -2.0f * v.y, az = -2.0f * v.z;
        qx2[k] = (f32x2){ax, ax};
        qy2[k] = (f32x2){ay, ay};
        qz2[k] = (f32x2){az, az};
        q2[k]  = v.w;
        mn[k]  = (f32x2){3.4e38f, 3.4e38f};
    }
    __syncthreads();

    // 2 pairs (4 db points) per iteration. Per k: 6 pk_fma + 2 min3.
    for (int j = 0; j < CHUNK; j += 4) {
        float4 lo0 = tile[j + 0];   // {x0,x1,y0,y1} of pair A (broadcast read)
        float4 hi0 = tile[j + 1];   // {z0,z1,w0,w1}
        float4 lo1 = tile[j + 2];   // pair B
        float4 hi1 = tile[j + 3];
        f32x2 px0 = {lo0.x, lo0.y}, py0 = {lo0.z, lo0.w};
        f32x2 pz0 = {hi0.x, hi0.y}, pw0 = {hi0.z, hi0.w};
        f32x2 px1 = {lo1.x, lo1.y}, py1 = {lo1.z, lo1.w};
        f32x2 pz1 = {hi1.x, hi1.y}, pw1 = {hi1.z, hi1.w};
#pragma unroll
        for (int k = 0; k < QPT; ++k) {
            f32x2 a0 = __builtin_elementwise_fma(qx2[k], px0, pw0);
            a0 = __builtin_elementwise_fma(qy2[k], py0, a0);
            a0 = __builtin_elementwise_fma(qz2[k], pz0, a0);
            f32x2 a1 = __builtin_elementwise_fma(qx2[k], px1, pw1);
            a1 = __builtin_elementwise_fma(qy2[k], py1, a1);
            a1 = __builtin_elementwise_fma(qz2[k], pz1, a1);
            // min(min(a0,a1), mn) per half -> v_min3_f32 x2
            mn[k] = __builtin_elementwise_min(
                        __builtin_elementwise_min(a0, a1), mn[k]);
        }
    }

    // d2 = max(min(mn.lo, mn.hi) + q2, 0) >= 0 -> uint compare == float compare
#pragma unroll
    for (int k = 0; k < QPT; ++k) {
        float d = fmaxf(fminf(mn[k].x, mn[k].y) + q2[k], 0.0f);
        atomicMin(&minOut[qbase + k * BLOCK + threadIdx.x], __float_as_uint(d));
    }
}

// Multi-block reduce: block partial sums -> one atomicAdd per block.
#define RBLOCKS 128
__global__ __launch_bounds__(BLOCK) void chamfer_reduce(
    const unsigned* __restrict__ minC, const unsigned* __restrict__ minT,
    float* __restrict__ out, int n, int m)
{
    __shared__ float red[4];
    float s = 0.0f;
    const float invn = 1.0f / (float)n, invm = 1.0f / (float)m;
    for (int i = blockIdx.x * BLOCK + threadIdx.x; i < n; i += RBLOCKS * BLOCK)
        s += __uint_as_float(minC[i]) * invn;
    for (int i = blockIdx.x * BLOCK + threadIdx.x; i < m; i += RBLOCKS * BLOCK)
        s += __uint_as_float(minT[i]) * invm;

#pragma unroll
    for (int off = 32; off > 0; off >>= 1) s += __shfl_down(s, off, 64);
    int wave = threadIdx.x >> 6;
    int lane = threadIdx.x & 63;
    if (lane == 0) red[wave] = s;
    __syncthreads();
    if (threadIdx.x == 0) {
        float t = red[0] + red[1] + red[2] + red[3];
        atomicAdd(out, t);
    }
}

extern "C" void kernel_launch(void* const* d_in, const int* in_sizes, int n_in,
                              void* d_out, int out_size, void* d_ws, size_t ws_size,
                              hipStream_t stream) {
    const float* Xc = (const float*)d_in[0];
    const float* Xt = (const float*)d_in[1];
    const int n = in_sizes[0] / 3;   // 16384
    const int m = in_sizes[1] / 3;   // 16384

    // ws: minC[n] u32 | minT[m] u32 | Pc[n] f4 | Pt[m] f4 | Tc[4n] f | Tt[4m] f
    unsigned* minC = (unsigned*)d_ws;
    unsigned* minT = minC + n;
    float4*   Pc   = (float4*)((char*)d_ws + (size_t)(n + m) * sizeof(unsigned));
    float4*   Pt   = Pc + n;
    float*    Tc   = (float*)(Pt + m);
    float*    Tt   = Tc + (size_t)4 * n;
    float*    out  = (float*)d_out;

    int prepBlocks = ((n > m ? n : m) + BLOCK - 1) / BLOCK;
    chamfer_prep<<<prepBlocks, BLOCK, 0, stream>>>(
        Xc, Xt, Pc, Pt, Tc, Tt, minC, minT, out, n, m);

    dim3 grid(n / (BLOCK * QPT), DCHUNKS, 2);   // 8 x 64 x 2 = 1024 blocks
    chamfer_pass<<<grid, BLOCK, 0, stream>>>(
        Pc, Pt, (const float4*)Tc, (const float4*)Tt, minC, minT);

    chamfer_reduce<<<RBLOCKS, BLOCK, 0, stream>>>(minC, minT, out, n, m);
}